// Round 2
// baseline (1481.989 us; speedup 1.0000x reference)
//
#include <hip/hip_runtime.h>
#include <cstddef>
#include <cstdint>

typedef __attribute__((ext_vector_type(8))) short short8v;
typedef __attribute__((ext_vector_type(4))) short short4v;
typedef __attribute__((ext_vector_type(4))) float floatx4;

__device__ __forceinline__ float b2f(short u){
    return __uint_as_float(((unsigned)(unsigned short)u) << 16);
}
__device__ __forceinline__ short f2b(float f){
    unsigned x = __float_as_uint(f);
    unsigned r = x + 0x7FFFu + ((x >> 16) & 1u);
    return (short)(r >> 16);
}
// dtype-adaptive loads (flags resolved on device, uniform branch)
__device__ __forceinline__ float loadF(const void* p, size_t i, int isBf16){
    return isBf16 ? b2f(((const short*)p)[i]) : ((const float*)p)[i];
}
__device__ __forceinline__ int loadI(const void* p, size_t i, int isI64){
    return isI64 ? ((const int*)p)[2 * i] : ((const int*)p)[i];
}

// ---- dtype detection: flags[0]=floats-are-bf16, flags[1]=ints-are-int64 ----
__global__ void detect_kernel(const void* feat, const void* ei, int E, int* flags){
    int lane = threadIdx.x;
    const unsigned short* fs = (const unsigned short*)feat;
    int plaus = 0;
    for (int j = lane; j < 128; j += 64){
        unsigned short s = fs[2 * j];            // even-indexed short
        int e = (s >> 7) & 0xFF;                 // bf16 exponent field
        if (s == 0 || (e >= 100 && e <= 140)) plaus++;
    }
    #pragma unroll
    for (int o = 32; o > 0; o >>= 1) plaus += __shfl_xor(plaus, o);
    const int* ew = (const int*)ei;
    int zeros = 0;
    for (int j = lane; j < 128; j += 64) if (ew[2 * j + 1] == 0) zeros++;
    #pragma unroll
    for (int o = 32; o > 0; o >>= 1) zeros += __shfl_xor(zeros, o);
    if (lane == 0){ flags[0] = (plaus >= 64) ? 1 : 0; flags[1] = (zeros >= 64) ? 1 : 0; }
    (void)E;
}

__global__ void sentinel_kernel(void* out, const int* flags, float v){
    if (threadIdx.x == 0){
        if (flags[0]) ((short*)out)[0] = f2b(v);
        else          ((float*)out)[0] = v;
    }
}

// ---------------- preprocessing: CSR by dst ----------------
__global__ void zero3(int* cnt, int* fill, unsigned* pool, int N){
    int i = blockIdx.x * 256 + threadIdx.x;
    if (i < N){ cnt[i] = 0; fill[i] = 0; }
    if (i < 256) pool[i] = 0u;
}

__global__ void hist_kernel(const void* __restrict__ ei, int* __restrict__ cnt, int E,
                            const int* __restrict__ flags){
    int i = blockIdx.x * 256 + threadIdx.x;
    if (i < E) atomicAdd(&cnt[loadI(ei, (size_t)E + i, flags[1])], 1);
}

__global__ void scan_kernel(const int* __restrict__ cnt, int* __restrict__ off, int N){
    __shared__ int wsum[16];
    __shared__ int base;
    const int t = threadIdx.x;
    const int w = t >> 6, lane = t & 63;
    if (t == 0) base = 0;
    __syncthreads();
    for (int s = 0; s < N; s += 1024){
        int v = (s + t < N) ? cnt[s + t] : 0;
        int x = v;
        #pragma unroll
        for (int o = 1; o < 64; o <<= 1){
            int y = __shfl_up(x, o);
            if (lane >= o) x += y;
        }
        if (lane == 63) wsum[w] = x;
        __syncthreads();
        if (w == 0){
            int mv = (lane < 16) ? wsum[lane] : 0;
            int xx = mv;
            #pragma unroll
            for (int o = 1; o < 16; o <<= 1){
                int y = __shfl_up(xx, o);
                if (lane >= o) xx += y;
            }
            if (lane < 16) wsum[lane] = xx - mv;
        }
        __syncthreads();
        int incl = x + wsum[w] + base;
        if (s + t < N) off[s + t] = incl - v;
        __syncthreads();
        if (t == 1023) base = incl;
        __syncthreads();
    }
    if (t == 0) off[N] = base;
}

__global__ void scatter_kernel(const void* __restrict__ ei, const void* __restrict__ ea,
                               const int* __restrict__ off, int* __restrict__ fill,
                               int* __restrict__ srcS, int* __restrict__ dstS,
                               float* __restrict__ eaS, int E, const int* __restrict__ flags){
    int i = blockIdx.x * 256 + threadIdx.x;
    if (i >= E) return;
    int d = loadI(ei, (size_t)E + i, flags[1]);
    int pos = off[d] + atomicAdd(&fill[d], 1);
    srcS[pos] = loadI(ei, (size_t)i, flags[1]);
    dstS[pos] = d;
    eaS[pos] = loadF(ea, (size_t)i, flags[0]);
}

// W [K x 256] -> BtH/BtL [256 x K] bf16 hi/lo split (lo=0 when input already bf16)
__global__ void prep_b(const void* __restrict__ W, short* __restrict__ bhi,
                       short* __restrict__ blo, int K, const int* __restrict__ flags){
    int idx = blockIdx.x * 256 + threadIdx.x;   // grid = K blocks
    int k = idx >> 8, c = idx & 255;
    float v = loadF(W, idx, flags[0]);
    short h = f2b(v);
    short l = f2b(v - b2f(h));
    bhi[(size_t)c * K + k] = h;
    blo[(size_t)c * K + k] = l;
}

__global__ void decode_f32(const void* __restrict__ in, float* __restrict__ out, int n,
                           const int* __restrict__ flags){
    int i = blockIdx.x * 256 + threadIdx.x;
    if (i < n) out[i] = loadF(in, (size_t)i, flags[0]);
}

// ---------------- split MFMA GEMM: C[M x 256] = A[M x K] * B, B given as Bt hi/lo ----------------
// A f32 (ws buffer, aRaw=0) or raw input (aRaw=1, dtype per flag). Exact to ~2^-15 rel.
__global__ __launch_bounds__(256) void gemm_split(const void* __restrict__ A, int aRaw,
        const short* __restrict__ BtH, const short* __restrict__ BtL,
        float* __restrict__ C, int M, int K, const int* __restrict__ flags){
    __shared__ __align__(16) short Ahi[64][72];
    __shared__ __align__(16) short Alo[64][72];
    __shared__ __align__(16) short BsH[64][72];
    __shared__ __align__(16) short BsL[64][72];
    const int fbf = flags[0];
    const int t = threadIdx.x;
    const int w = t >> 6, lane = t & 63;
    const int bRow = blockIdx.x * 64;
    const int bCol = blockIdx.y * 64;
    floatx4 acc[4];
    #pragma unroll
    for (int i = 0; i < 4; i++) acc[i] = (floatx4){0.f, 0.f, 0.f, 0.f};

    for (int k0 = 0; k0 < K; k0 += 64){
        #pragma unroll
        for (int i = 0; i < 4; i++){
            int id = t + i * 256;
            int r = id >> 4;
            int c4 = (id & 15) << 2;
            int gr = bRow + r; if (gr >= M) gr = M - 1;
            size_t gidx = (size_t)gr * K + k0 + c4;
            floatx4 v;
            if (aRaw && fbf){
                short4v s = *(const short4v*)&((const short*)A)[gidx];
                v = (floatx4){ b2f(s[0]), b2f(s[1]), b2f(s[2]), b2f(s[3]) };
            } else {
                v = *(const floatx4*)&((const float*)A)[gidx];
            }
            short4v h, l;
            #pragma unroll
            for (int j = 0; j < 4; j++){
                short hj = f2b(v[j]);
                h[j] = hj;
                l[j] = f2b(v[j] - b2f(hj));
            }
            *(short4v*)&Ahi[r][c4] = h;
            *(short4v*)&Alo[r][c4] = l;
        }
        #pragma unroll
        for (int i = 0; i < 2; i++){
            int id = t + i * 256;
            int r = id >> 3;
            int c8 = (id & 7) << 3;
            size_t bidx = (size_t)(bCol + r) * K + k0 + c8;
            *(short8v*)&BsH[r][c8] = *(const short8v*)&BtH[bidx];
            *(short8v*)&BsL[r][c8] = *(const short8v*)&BtL[bidx];
        }
        __syncthreads();
        const int arow = (w << 4) + (lane & 15);
        const int kk = (lane >> 4) << 3;
        #pragma unroll
        for (int ks = 0; ks < 64; ks += 32){
            short8v ah = *(const short8v*)&Ahi[arow][ks + kk];
            short8v al = *(const short8v*)&Alo[arow][ks + kk];
            #pragma unroll
            for (int ct = 0; ct < 4; ct++){
                short8v bh = *(const short8v*)&BsH[ct * 16 + (lane & 15)][ks + kk];
                short8v bl = *(const short8v*)&BsL[ct * 16 + (lane & 15)][ks + kk];
                acc[ct] = __builtin_amdgcn_mfma_f32_16x16x32_bf16(al, bh, acc[ct], 0, 0, 0);
                acc[ct] = __builtin_amdgcn_mfma_f32_16x16x32_bf16(ah, bl, acc[ct], 0, 0, 0);
                acc[ct] = __builtin_amdgcn_mfma_f32_16x16x32_bf16(ah, bh, acc[ct], 0, 0, 0);
            }
        }
        __syncthreads();
    }
    const int rbase = bRow + (w << 4) + ((lane >> 4) << 2);
    const int cb = bCol + (lane & 15);
    #pragma unroll
    for (int ct = 0; ct < 4; ct++){
        #pragma unroll
        for (int r = 0; r < 4; r++){
            int gr = rbase + r;
            if (gr < M) C[(size_t)gr * 256 + cb + ct * 16] = acc[ct][r];
        }
    }
}

// ---------------- per-edge attention logit (CSR-sorted edges) ----------------
__global__ __launch_bounds__(256) void edge_scores(const float* __restrict__ xl,
        const float* __restrict__ xr, const int* __restrict__ srcS,
        const int* __restrict__ dstS, const float* __restrict__ eaS,
        const float* __restrict__ WeF, const float* __restrict__ attF,
        float* __restrict__ score, int E){
    int e = blockIdx.x * 4 + (threadIdx.x >> 6);
    int lane = threadIdx.x & 63;
    if (e >= E) return;
    int s = srcS[e], d = dstS[e];
    float ea = eaS[e];
    int dd = lane << 2;
    floatx4 vl = *(const floatx4*)&xl[(size_t)s * 256 + dd];
    floatx4 vr = *(const floatx4*)&xr[(size_t)d * 256 + dd];
    floatx4 vw = *(const floatx4*)&WeF[dd];
    floatx4 va = *(const floatx4*)&attF[dd];
    float p = 0.f;
    #pragma unroll
    for (int j = 0; j < 4; j++){
        float m = vl[j] + vr[j] + ea * vw[j];
        float lr = m > 0.f ? m : 0.2f * m;
        p += lr * va[j];
    }
    #pragma unroll
    for (int o = 32; o > 0; o >>= 1) p += __shfl_xor(p, o);
    if (lane == 0) score[e] = p;
}

// ---------------- per-node softmax + aggregation + bias + relu ----------------
__global__ __launch_bounds__(256) void node_aggregate(const float* __restrict__ xl,
        const float* __restrict__ score, const int* __restrict__ srcS,
        const int* __restrict__ off, const float* __restrict__ bbF,
        float* __restrict__ xout, int N){
    int node = blockIdx.x * 4 + (threadIdx.x >> 6);
    int lane = threadIdx.x & 63;
    if (node >= N) return;
    int beg = off[node], end = off[node + 1];
    float m = -3.4e38f;
    for (int k = beg + lane; k < end; k += 64) m = fmaxf(m, score[k]);
    #pragma unroll
    for (int o = 32; o > 0; o >>= 1) m = fmaxf(m, __shfl_xor(m, o));
    float ssum = 0.f;
    for (int k = beg + lane; k < end; k += 64) ssum += __expf(score[k] - m);
    #pragma unroll
    for (int o = 32; o > 0; o >>= 1) ssum += __shfl_xor(ssum, o);
    float inv = (end > beg) ? 1.f / ssum : 0.f;
    int dd = lane << 2;
    floatx4 a = (floatx4){0.f, 0.f, 0.f, 0.f};
    for (int k = beg; k < end; ++k){
        float al = __expf(score[k] - m);
        int sj = srcS[k];
        floatx4 v = *(const floatx4*)&xl[(size_t)sj * 256 + dd];
        a[0] += al * v[0]; a[1] += al * v[1]; a[2] += al * v[2]; a[3] += al * v[3];
    }
    floatx4 o4;
    o4[0] = fmaxf(a[0] * inv + bbF[dd + 0], 0.f);
    o4[1] = fmaxf(a[1] * inv + bbF[dd + 1], 0.f);
    o4[2] = fmaxf(a[2] * inv + bbF[dd + 2], 0.f);
    o4[3] = fmaxf(a[3] * inv + bbF[dd + 3], 0.f);
    *(floatx4*)&xout[(size_t)node * 256 + dd] = o4;
}

// ---------------- global max pool (post-relu >= 0 -> uint atomicMax valid) ----------------
__global__ __launch_bounds__(256) void col_max(const float* __restrict__ x,
        unsigned* __restrict__ pool, int N){
    int lane = threadIdx.x & 63;
    int w = threadIdx.x >> 6;
    int dd = lane << 2;
    floatx4 mx = (floatx4){0.f, 0.f, 0.f, 0.f};
    for (int r = blockIdx.x * 4 + w; r < N; r += gridDim.x * 4){
        floatx4 v = *(const floatx4*)&x[(size_t)r * 256 + dd];
        mx[0] = fmaxf(mx[0], v[0]); mx[1] = fmaxf(mx[1], v[1]);
        mx[2] = fmaxf(mx[2], v[2]); mx[3] = fmaxf(mx[3], v[3]);
    }
    atomicMax(&pool[dd + 0], __float_as_uint(mx[0]));
    atomicMax(&pool[dd + 1], __float_as_uint(mx[1]));
    atomicMax(&pool[dd + 2], __float_as_uint(mx[2]));
    atomicMax(&pool[dd + 3], __float_as_uint(mx[3]));
}

__global__ void head_kernel(const unsigned* __restrict__ pool, const float* __restrict__ Wh1F,
        const float* __restrict__ bh1F, const float* __restrict__ Wh2F,
        const float* __restrict__ bh2F, void* __restrict__ out, const int* __restrict__ flags){
    int lane = threadIdx.x;
    float acc = 0.f;
    if (lane < 10){
        acc = bh1F[lane];
        for (int d = 0; d < 256; ++d)
            acc += __uint_as_float(pool[d]) * Wh1F[d * 10 + lane];
        acc = fmaxf(acc, 0.f) * Wh2F[lane];
    }
    #pragma unroll
    for (int o = 32; o > 0; o >>= 1) acc += __shfl_xor(acc, o);
    if (lane == 0){
        float r = acc + bh2F[0];
        if (flags[0]) ((short*)out)[0] = f2b(r);
        else          ((float*)out)[0] = r;
    }
}

extern "C" void kernel_launch(void* const* d_in, const int* in_sizes, int n_in,
                              void* d_out, int out_size, void* d_ws, size_t ws_size,
                              hipStream_t stream){
    const void* feat = d_in[0];
    const void* ei   = d_in[1];
    const void* ea   = d_in[2];
    const void* Wl[3] = {d_in[3], d_in[8],  d_in[13]};
    const void* Wr[3] = {d_in[4], d_in[9],  d_in[14]};
    const void* We[3] = {d_in[5], d_in[10], d_in[15]};
    const void* at[3] = {d_in[6], d_in[11], d_in[16]};
    const void* bb[3] = {d_in[7], d_in[12], d_in[17]};
    const void* Wh1 = d_in[18];
    const void* bh1 = d_in[19];
    const void* Wh2 = d_in[20];
    const void* bh2 = d_in[21];

    const int N = in_sizes[0] / 128;
    const int E = in_sizes[1] / 2;
    const int Kin[3] = {128, 256, 256};

    char* p = (char*)d_ws;
    auto alloc = [&](size_t bytes) -> void* {
        void* r = (void*)p; p += (bytes + 255) & ~(size_t)255; return r;
    };
    int*   flags = (int*)alloc(256);
    int*   off   = (int*)alloc((size_t)(N + 1) * 4);
    int*   cnt   = (int*)alloc((size_t)N * 4);
    int*   fill  = (int*)alloc((size_t)N * 4);
    int*   srcS  = (int*)alloc((size_t)E * 4);
    int*   dstS  = (int*)alloc((size_t)E * 4);
    float* eaS   = (float*)alloc((size_t)E * 4);
    float* score = (float*)alloc((size_t)E * 4);
    float* P     = (float*)alloc((size_t)N * 256 * 4);
    float* Q     = (float*)alloc((size_t)N * 256 * 4);
    float* R     = (float*)alloc((size_t)N * 256 * 4);
    short* BtH[3]; short* BtL[3]; short* BtHr[3]; short* BtLr[3];
    for (int i = 0; i < 3; i++){
        BtH[i]  = (short*)alloc((size_t)Kin[i] * 256 * 2);
        BtL[i]  = (short*)alloc((size_t)Kin[i] * 256 * 2);
        BtHr[i] = (short*)alloc((size_t)Kin[i] * 256 * 2);
        BtLr[i] = (short*)alloc((size_t)Kin[i] * 256 * 2);
    }
    float* WeF  = (float*)alloc(3 * 256 * 4);
    float* attF = (float*)alloc(3 * 256 * 4);
    float* bbF  = (float*)alloc(3 * 256 * 4);
    float* Wh1F = (float*)alloc(2560 * 4);
    float* bh1F = (float*)alloc(16 * 4);
    float* Wh2F = (float*)alloc(16 * 4);
    float* bh2F = (float*)alloc(4 * 4);
    unsigned* pool = (unsigned*)alloc(256 * 4);
    size_t need = (size_t)(p - (char*)d_ws);

    detect_kernel<<<dim3(1), dim3(64), 0, stream>>>(feat, ei, E, flags);
    sentinel_kernel<<<dim3(1), dim3(1), 0, stream>>>(d_out, flags, 777.0f);
    if (need > ws_size){
        sentinel_kernel<<<dim3(1), dim3(1), 0, stream>>>(d_out, flags, 555.0f);
        return;
    }

    zero3<<<dim3((N + 255) / 256), dim3(256), 0, stream>>>(cnt, fill, pool, N);
    hist_kernel<<<dim3((E + 255) / 256), dim3(256), 0, stream>>>(ei, cnt, E, flags);
    scan_kernel<<<dim3(1), dim3(1024), 0, stream>>>(cnt, off, N);
    scatter_kernel<<<dim3((E + 255) / 256), dim3(256), 0, stream>>>(ei, ea, off, fill,
                                                                    srcS, dstS, eaS, E, flags);
    for (int i = 0; i < 3; i++){
        prep_b<<<dim3(Kin[i]), dim3(256), 0, stream>>>(Wl[i], BtH[i],  BtL[i],  Kin[i], flags);
        prep_b<<<dim3(Kin[i]), dim3(256), 0, stream>>>(Wr[i], BtHr[i], BtLr[i], Kin[i], flags);
        decode_f32<<<dim3(1), dim3(256), 0, stream>>>(We[i], WeF + i * 256, 256, flags);
        decode_f32<<<dim3(1), dim3(256), 0, stream>>>(at[i], attF + i * 256, 256, flags);
        decode_f32<<<dim3(1), dim3(256), 0, stream>>>(bb[i], bbF + i * 256, 256, flags);
    }
    decode_f32<<<dim3(10), dim3(256), 0, stream>>>(Wh1, Wh1F, 2560, flags);
    decode_f32<<<dim3(1), dim3(256), 0, stream>>>(bh1, bh1F, 10, flags);
    decode_f32<<<dim3(1), dim3(256), 0, stream>>>(Wh2, Wh2F, 10, flags);
    decode_f32<<<dim3(1), dim3(256), 0, stream>>>(bh2, bh2F, 1, flags);

    dim3 gemm_grid((N + 63) / 64, 4);
    for (int L = 0; L < 3; L++){
        const void* A = (L == 0) ? feat : (const void*)Q;
        int aRaw = (L == 0) ? 1 : 0;
        float* xr = (L == 0) ? Q : R;
        gemm_split<<<gemm_grid, dim3(256), 0, stream>>>(A, aRaw, BtH[L], BtL[L],
                                                        P, N, Kin[L], flags);
        gemm_split<<<gemm_grid, dim3(256), 0, stream>>>(A, aRaw, BtHr[L], BtLr[L],
                                                        xr, N, Kin[L], flags);
        edge_scores<<<dim3((E + 3) / 4), dim3(256), 0, stream>>>(P, xr, srcS, dstS, eaS,
                                                                 WeF + L * 256, attF + L * 256,
                                                                 score, E);
        node_aggregate<<<dim3((N + 3) / 4), dim3(256), 0, stream>>>(P, score, srcS, off,
                                                                    bbF + L * 256, Q, N);
    }
    col_max<<<dim3(256), dim3(256), 0, stream>>>(Q, pool, N);
    head_kernel<<<dim3(1), dim3(64), 0, stream>>>(pool, Wh1F, bh1F, Wh2F, bh2F, d_out, flags);
    (void)n_in; (void)out_size;
}

// Round 3
// 1003.810 us; speedup vs baseline: 1.4764x; 1.4764x over previous
//
#include <hip/hip_runtime.h>
#include <cstddef>
#include <cstdint>

typedef __attribute__((ext_vector_type(8))) short short8v;
typedef __attribute__((ext_vector_type(4))) short short4v;
typedef __attribute__((ext_vector_type(4))) float floatx4;

__device__ __forceinline__ float b2f(short u){
    return __uint_as_float(((unsigned)(unsigned short)u) << 16);
}
__device__ __forceinline__ short f2b(float f){
    unsigned x = __float_as_uint(f);
    unsigned r = x + 0x7FFFu + ((x >> 16) & 1u);
    return (short)(r >> 16);
}
__device__ __forceinline__ float loadF(const void* p, size_t i, int isBf16){
    return isBf16 ? b2f(((const short*)p)[i]) : ((const float*)p)[i];
}
__device__ __forceinline__ int loadI(const void* p, size_t i, int isI64){
    return isI64 ? ((const int*)p)[2 * i] : ((const int*)p)[i];
}

// ---- dtype detection; also zeroes the 8 "hasLo" flags (slots 8..15) ----
__global__ void detect_kernel(const void* feat, const void* ei, int E, int* flags){
    int lane = threadIdx.x;
    if (lane >= 8 && lane < 16) flags[lane] = 0;
    const unsigned short* fs = (const unsigned short*)feat;
    int plaus = 0;
    for (int j = lane; j < 128; j += 64){
        unsigned short s = fs[2 * j];
        int e = (s >> 7) & 0xFF;
        if (s == 0 || (e >= 100 && e <= 140)) plaus++;
    }
    #pragma unroll
    for (int o = 32; o > 0; o >>= 1) plaus += __shfl_xor(plaus, o);
    const int* ew = (const int*)ei;
    int zeros = 0;
    for (int j = lane; j < 128; j += 64) if (ew[2 * j + 1] == 0) zeros++;
    #pragma unroll
    for (int o = 32; o > 0; o >>= 1) zeros += __shfl_xor(zeros, o);
    if (lane == 0){ flags[0] = (plaus >= 64) ? 1 : 0; flags[1] = (zeros >= 64) ? 1 : 0; }
    (void)E;
}

__global__ void sentinel_kernel(void* out, const int* flags, float v){
    if (threadIdx.x == 0){
        if (flags[0]) ((short*)out)[0] = f2b(v);
        else          ((float*)out)[0] = v;
    }
}

// ---------------- preprocessing: CSR by dst ----------------
__global__ void zero3(int* cnt, int* fill, unsigned* pool, int N){
    int i = blockIdx.x * 256 + threadIdx.x;
    if (i < N){ cnt[i] = 0; fill[i] = 0; }
    if (i < 256) pool[i] = 0u;
}

__global__ void hist_kernel(const void* __restrict__ ei, int* __restrict__ cnt, int E,
                            const int* __restrict__ flags){
    int i = blockIdx.x * 256 + threadIdx.x;
    if (i < E) atomicAdd(&cnt[loadI(ei, (size_t)E + i, flags[1])], 1);
}

__global__ void scan_kernel(const int* __restrict__ cnt, int* __restrict__ off, int N){
    __shared__ int wsum[16];
    __shared__ int base;
    const int t = threadIdx.x;
    const int w = t >> 6, lane = t & 63;
    if (t == 0) base = 0;
    __syncthreads();
    for (int s = 0; s < N; s += 1024){
        int v = (s + t < N) ? cnt[s + t] : 0;
        int x = v;
        #pragma unroll
        for (int o = 1; o < 64; o <<= 1){
            int y = __shfl_up(x, o);
            if (lane >= o) x += y;
        }
        if (lane == 63) wsum[w] = x;
        __syncthreads();
        if (w == 0){
            int mv = (lane < 16) ? wsum[lane] : 0;
            int xx = mv;
            #pragma unroll
            for (int o = 1; o < 16; o <<= 1){
                int y = __shfl_up(xx, o);
                if (lane >= o) xx += y;
            }
            if (lane < 16) wsum[lane] = xx - mv;
        }
        __syncthreads();
        int incl = x + wsum[w] + base;
        if (s + t < N) off[s + t] = incl - v;
        __syncthreads();
        if (t == 1023) base = incl;
        __syncthreads();
    }
    if (t == 0) off[N] = base;
}

__global__ void scatter_kernel(const void* __restrict__ ei, const void* __restrict__ ea,
                               const int* __restrict__ off, int* __restrict__ fill,
                               int* __restrict__ srcS, float* __restrict__ eaS,
                               int E, const int* __restrict__ flags){
    int i = blockIdx.x * 256 + threadIdx.x;
    if (i >= E) return;
    int d = loadI(ei, (size_t)E + i, flags[1]);
    int pos = off[d] + atomicAdd(&fill[d], 1);
    srcS[pos] = loadI(ei, (size_t)i, flags[1]);
    eaS[pos] = loadF(ea, (size_t)i, flags[0]);
}

// W [K x 256] -> BtH/BtL [256 x K] bf16 hi/lo split; sets *hasLo if any lo != 0
__global__ void prep_b(const void* __restrict__ W, short* __restrict__ bhi,
                       short* __restrict__ blo, int K, const int* __restrict__ flags,
                       int* __restrict__ hasLo){
    int idx = blockIdx.x * 256 + threadIdx.x;   // grid = K blocks
    int k = idx >> 8, c = idx & 255;
    float v = loadF(W, idx, flags[0]);
    short h = f2b(v);
    short l = f2b(v - b2f(h));
    bhi[(size_t)c * K + k] = h;
    blo[(size_t)c * K + k] = l;
    if (__ballot(l != 0) != 0ull && (threadIdx.x & 63) == 0) atomicOr(hasLo, 1);
}

// fused small-array decode: 13 jobs in one launch
struct DJob { const void* src; float* dst; int n; };
struct DJobs { DJob j[13]; };
__global__ void decode_many(DJobs jobs, const int* __restrict__ flags){
    const DJob J = jobs.j[blockIdx.x];
    int fbf = flags[0];
    for (int i = threadIdx.x; i < J.n; i += 256)
        J.dst[i] = loadF(J.src, (size_t)i, fbf);
}

// ---------------- split MFMA GEMM with zero-lo skipping ----------------
__global__ __launch_bounds__(256) void gemm_split(const void* __restrict__ A, int aRaw,
        const short* __restrict__ BtH, const short* __restrict__ BtL,
        float* __restrict__ C, int M, int K, const int* __restrict__ flags,
        const int* __restrict__ bHasLo){
    __shared__ __align__(16) short Ahi[64][72];
    __shared__ __align__(16) short Alo[64][72];
    __shared__ __align__(16) short BsH[64][72];
    __shared__ __align__(16) short BsL[64][72];
    const int fbf = flags[0];
    const int az = (aRaw && fbf) ? 1 : 0;   // A lo == 0 (A already exact bf16)
    const int bz = bHasLo[0] ? 0 : 1;       // B lo == 0
    const int t = threadIdx.x;
    const int w = t >> 6, lane = t & 63;
    const int bRow = blockIdx.x * 64;
    const int bCol = blockIdx.y * 64;
    floatx4 acc[4];
    #pragma unroll
    for (int i = 0; i < 4; i++) acc[i] = (floatx4){0.f, 0.f, 0.f, 0.f};

    for (int k0 = 0; k0 < K; k0 += 64){
        #pragma unroll
        for (int i = 0; i < 4; i++){
            int id = t + i * 256;
            int r = id >> 4;
            int c4 = (id & 15) << 2;
            int gr = bRow + r; if (gr >= M) gr = M - 1;
            size_t gidx = (size_t)gr * K + k0 + c4;
            if (az){
                *(short4v*)&Ahi[r][c4] = *(const short4v*)&((const short*)A)[gidx];
            } else {
                floatx4 v = *(const floatx4*)&((const float*)A)[gidx];
                short4v h, l;
                #pragma unroll
                for (int j = 0; j < 4; j++){
                    short hj = f2b(v[j]);
                    h[j] = hj;
                    l[j] = f2b(v[j] - b2f(hj));
                }
                *(short4v*)&Ahi[r][c4] = h;
                *(short4v*)&Alo[r][c4] = l;
            }
        }
        #pragma unroll
        for (int i = 0; i < 2; i++){
            int id = t + i * 256;
            int r = id >> 3;
            int c8 = (id & 7) << 3;
            size_t bidx = (size_t)(bCol + r) * K + k0 + c8;
            *(short8v*)&BsH[r][c8] = *(const short8v*)&BtH[bidx];
            if (!bz) *(short8v*)&BsL[r][c8] = *(const short8v*)&BtL[bidx];
        }
        __syncthreads();
        const int arow = (w << 4) + (lane & 15);
        const int kk = (lane >> 4) << 3;
        #pragma unroll
        for (int ks = 0; ks < 64; ks += 32){
            short8v ah = *(const short8v*)&Ahi[arow][ks + kk];
            short8v al = *(const short8v*)&Alo[arow][ks + kk];  // unused if az
            #pragma unroll
            for (int ct = 0; ct < 4; ct++){
                short8v bh = *(const short8v*)&BsH[ct * 16 + (lane & 15)][ks + kk];
                if (!az) acc[ct] = __builtin_amdgcn_mfma_f32_16x16x32_bf16(al, bh, acc[ct], 0, 0, 0);
                if (!bz){
                    short8v bl = *(const short8v*)&BsL[ct * 16 + (lane & 15)][ks + kk];
                    acc[ct] = __builtin_amdgcn_mfma_f32_16x16x32_bf16(ah, bl, acc[ct], 0, 0, 0);
                }
                acc[ct] = __builtin_amdgcn_mfma_f32_16x16x32_bf16(ah, bh, acc[ct], 0, 0, 0);
            }
        }
        __syncthreads();
    }
    const int rbase = bRow + (w << 4) + ((lane >> 4) << 2);
    const int cb = bCol + (lane & 15);
    #pragma unroll
    for (int ct = 0; ct < 4; ct++){
        #pragma unroll
        for (int r = 0; r < 4; r++){
            int gr = rbase + r;
            if (gr < M) C[(size_t)gr * 256 + cb + ct * 16] = acc[ct][r];
        }
    }
}

// ------- fused per-node: scores + online softmax + aggregation + bias + relu -------
// one wave per node; edges in chunks of 8 for memory-level parallelism
__global__ __launch_bounds__(256) void fused_agg(const float* __restrict__ xl,
        const float* __restrict__ xr, const int* __restrict__ srcS,
        const float* __restrict__ eaS, const int* __restrict__ off,
        const float* __restrict__ WeF, const float* __restrict__ attF,
        const float* __restrict__ bbF, float* __restrict__ xout, int N){
    int node = blockIdx.x * 4 + (threadIdx.x >> 6);
    int lane = threadIdx.x & 63;
    if (node >= N) return;
    const int beg = off[node], end = off[node + 1];
    const int dd = lane << 2;
    const floatx4 xr4 = *(const floatx4*)&xr[(size_t)node * 256 + dd];
    const floatx4 we4 = *(const floatx4*)&WeF[dd];
    const floatx4 at4 = *(const floatx4*)&attF[dd];
    float m = -1e30f, ssum = 0.f;
    floatx4 a4 = (floatx4){0.f, 0.f, 0.f, 0.f};
    for (int k0 = beg; k0 < end; k0 += 8){
        floatx4 v[8]; float pp[8]; float eav[8];
        #pragma unroll
        for (int c = 0; c < 8; c++){
            int k = k0 + c; if (k >= end) k = end - 1;   // clamped (masked later)
            int s = srcS[k];
            eav[c] = eaS[k];
            v[c] = *(const floatx4*)&xl[(size_t)s * 256 + dd];
        }
        #pragma unroll
        for (int c = 0; c < 8; c++){
            float p = 0.f;
            #pragma unroll
            for (int j = 0; j < 4; j++){
                float tv = v[c][j] + xr4[j] + eav[c] * we4[j];
                tv = tv > 0.f ? tv : 0.2f * tv;
                p += tv * at4[j];
            }
            #pragma unroll
            for (int o = 32; o > 0; o >>= 1) p += __shfl_xor(p, o);
            pp[c] = (k0 + c < end) ? p : -1e30f;
        }
        float pm = pp[0];
        #pragma unroll
        for (int c = 1; c < 8; c++) pm = fmaxf(pm, pp[c]);
        float newm = fmaxf(m, pm);
        float scale = __expf(m - newm);       // 0 on first chunk, 1 if max unchanged
        ssum *= scale;
        a4[0] *= scale; a4[1] *= scale; a4[2] *= scale; a4[3] *= scale;
        #pragma unroll
        for (int c = 0; c < 8; c++){
            float wgt = __expf(pp[c] - newm); // 0 for padded slots
            ssum += wgt;
            a4[0] += wgt * v[c][0]; a4[1] += wgt * v[c][1];
            a4[2] += wgt * v[c][2]; a4[3] += wgt * v[c][3];
        }
        m = newm;
    }
    float inv = (end > beg) ? 1.f / ssum : 0.f;
    floatx4 o4;
    o4[0] = fmaxf(a4[0] * inv + bbF[dd + 0], 0.f);
    o4[1] = fmaxf(a4[1] * inv + bbF[dd + 1], 0.f);
    o4[2] = fmaxf(a4[2] * inv + bbF[dd + 2], 0.f);
    o4[3] = fmaxf(a4[3] * inv + bbF[dd + 3], 0.f);
    *(floatx4*)&xout[(size_t)node * 256 + dd] = o4;
}

// ---------------- global max pool (post-relu >= 0 -> uint atomicMax valid) ----------------
__global__ __launch_bounds__(256) void col_max(const float* __restrict__ x,
        unsigned* __restrict__ pool, int N){
    int lane = threadIdx.x & 63;
    int w = threadIdx.x >> 6;
    int dd = lane << 2;
    floatx4 mx = (floatx4){0.f, 0.f, 0.f, 0.f};
    for (int r = blockIdx.x * 4 + w; r < N; r += gridDim.x * 4){
        floatx4 v = *(const floatx4*)&x[(size_t)r * 256 + dd];
        mx[0] = fmaxf(mx[0], v[0]); mx[1] = fmaxf(mx[1], v[1]);
        mx[2] = fmaxf(mx[2], v[2]); mx[3] = fmaxf(mx[3], v[3]);
    }
    atomicMax(&pool[dd + 0], __float_as_uint(mx[0]));
    atomicMax(&pool[dd + 1], __float_as_uint(mx[1]));
    atomicMax(&pool[dd + 2], __float_as_uint(mx[2]));
    atomicMax(&pool[dd + 3], __float_as_uint(mx[3]));
}

__global__ void head_kernel(const unsigned* __restrict__ pool, const float* __restrict__ Wh1F,
        const float* __restrict__ bh1F, const float* __restrict__ Wh2F,
        const float* __restrict__ bh2F, void* __restrict__ out, const int* __restrict__ flags){
    int lane = threadIdx.x;
    float acc = 0.f;
    if (lane < 10){
        acc = bh1F[lane];
        for (int d = 0; d < 256; ++d)
            acc += __uint_as_float(pool[d]) * Wh1F[d * 10 + lane];
        acc = fmaxf(acc, 0.f) * Wh2F[lane];
    }
    #pragma unroll
    for (int o = 32; o > 0; o >>= 1) acc += __shfl_xor(acc, o);
    if (lane == 0){
        float r = acc + bh2F[0];
        if (flags[0]) ((short*)out)[0] = f2b(r);
        else          ((float*)out)[0] = r;
    }
}

extern "C" void kernel_launch(void* const* d_in, const int* in_sizes, int n_in,
                              void* d_out, int out_size, void* d_ws, size_t ws_size,
                              hipStream_t stream){
    const void* feat = d_in[0];
    const void* ei   = d_in[1];
    const void* ea   = d_in[2];
    const void* Wl[3] = {d_in[3], d_in[8],  d_in[13]};
    const void* Wr[3] = {d_in[4], d_in[9],  d_in[14]};
    const void* We[3] = {d_in[5], d_in[10], d_in[15]};
    const void* at[3] = {d_in[6], d_in[11], d_in[16]};
    const void* bb[3] = {d_in[7], d_in[12], d_in[17]};
    const void* Wh1 = d_in[18];
    const void* bh1 = d_in[19];
    const void* Wh2 = d_in[20];
    const void* bh2 = d_in[21];

    const int N = in_sizes[0] / 128;
    const int E = in_sizes[1] / 2;
    const int Kin[3] = {128, 256, 256};

    char* p = (char*)d_ws;
    auto alloc = [&](size_t bytes) -> void* {
        void* r = (void*)p; p += (bytes + 255) & ~(size_t)255; return r;
    };
    int*   flags = (int*)alloc(256);
    int*   off   = (int*)alloc((size_t)(N + 1) * 4);
    int*   cnt   = (int*)alloc((size_t)N * 4);
    int*   fill  = (int*)alloc((size_t)N * 4);
    int*   srcS  = (int*)alloc((size_t)E * 4);
    float* eaS   = (float*)alloc((size_t)E * 4);
    float* P     = (float*)alloc((size_t)N * 256 * 4);
    float* Q     = (float*)alloc((size_t)N * 256 * 4);
    float* R     = (float*)alloc((size_t)N * 256 * 4);
    short* BtH[3]; short* BtL[3]; short* BtHr[3]; short* BtLr[3];
    for (int i = 0; i < 3; i++){
        BtH[i]  = (short*)alloc((size_t)Kin[i] * 256 * 2);
        BtL[i]  = (short*)alloc((size_t)Kin[i] * 256 * 2);
        BtHr[i] = (short*)alloc((size_t)Kin[i] * 256 * 2);
        BtLr[i] = (short*)alloc((size_t)Kin[i] * 256 * 2);
    }
    float* WeF  = (float*)alloc(3 * 256 * 4);
    float* attF = (float*)alloc(3 * 256 * 4);
    float* bbF  = (float*)alloc(3 * 256 * 4);
    float* Wh1F = (float*)alloc(2560 * 4);
    float* bh1F = (float*)alloc(16 * 4);
    float* Wh2F = (float*)alloc(16 * 4);
    float* bh2F = (float*)alloc(4 * 4);
    unsigned* pool = (unsigned*)alloc(256 * 4);
    size_t need = (size_t)(p - (char*)d_ws);

    detect_kernel<<<dim3(1), dim3(64), 0, stream>>>(feat, ei, E, flags);
    sentinel_kernel<<<dim3(1), dim3(1), 0, stream>>>(d_out, flags, 777.0f);
    if (need > ws_size){
        sentinel_kernel<<<dim3(1), dim3(1), 0, stream>>>(d_out, flags, 555.0f);
        return;
    }

    zero3<<<dim3((N + 255) / 256), dim3(256), 0, stream>>>(cnt, fill, pool, N);
    hist_kernel<<<dim3((E + 255) / 256), dim3(256), 0, stream>>>(ei, cnt, E, flags);
    scan_kernel<<<dim3(1), dim3(1024), 0, stream>>>(cnt, off, N);
    scatter_kernel<<<dim3((E + 255) / 256), dim3(256), 0, stream>>>(ei, ea, off, fill,
                                                                    srcS, eaS, E, flags);
    for (int i = 0; i < 3; i++){
        prep_b<<<dim3(Kin[i]), dim3(256), 0, stream>>>(Wl[i], BtH[i],  BtL[i],  Kin[i],
                                                       flags, &flags[8 + i]);
        prep_b<<<dim3(Kin[i]), dim3(256), 0, stream>>>(Wr[i], BtHr[i], BtLr[i], Kin[i],
                                                       flags, &flags[11 + i]);
    }
    DJobs jobs;
    for (int i = 0; i < 3; i++){
        jobs.j[i]     = { We[i], WeF  + i * 256, 256 };
        jobs.j[3 + i] = { at[i], attF + i * 256, 256 };
        jobs.j[6 + i] = { bb[i], bbF  + i * 256, 256 };
    }
    jobs.j[9]  = { Wh1, Wh1F, 2560 };
    jobs.j[10] = { bh1, bh1F, 10 };
    jobs.j[11] = { Wh2, Wh2F, 10 };
    jobs.j[12] = { bh2, bh2F, 1 };
    decode_many<<<dim3(13), dim3(256), 0, stream>>>(jobs, flags);

    dim3 gemm_grid((N + 63) / 64, 4);
    for (int L = 0; L < 3; L++){
        const void* A = (L == 0) ? feat : (const void*)Q;
        int aRaw = (L == 0) ? 1 : 0;
        gemm_split<<<gemm_grid, dim3(256), 0, stream>>>(A, aRaw, BtH[L], BtL[L],
                                                        P, N, Kin[L], flags, &flags[8 + L]);
        gemm_split<<<gemm_grid, dim3(256), 0, stream>>>(A, aRaw, BtHr[L], BtLr[L],
                                                        R, N, Kin[L], flags, &flags[11 + L]);
        fused_agg<<<dim3((N + 3) / 4), dim3(256), 0, stream>>>(P, R, srcS, eaS, off,
                                                               WeF + L * 256, attF + L * 256,
                                                               bbF + L * 256, Q, N);
    }
    col_max<<<dim3(256), dim3(256), 0, stream>>>(Q, pool, N);
    head_kernel<<<dim3(1), dim3(64), 0, stream>>>(pool, Wh1F, bh1F, Wh2F, bh2F, d_out, flags);
    (void)n_in; (void)out_size;
}